// Round 1
// baseline (1011.451 us; speedup 1.0000x reference)
//
#include <hip/hip_runtime.h>

// B-spline dense scatter: out[row, col] = value_k(xs[row]) when
// col == floor(xs[row]) + k (k in 0..3), else 0.
// value_k = sum_p x_loc^p * B[k][p], x_loc = frac(x) + (3 - k).
// Output is 131072 x 2048 f32 = 1 GiB -> pure HBM-write-bound stream.

__global__ __launch_bounds__(256) void bspline_row_kernel(
    const float* __restrict__ xs,
    const float* __restrict__ B,   // [4][4] ascending-power coeffs
    float* __restrict__ out,
    int n_knots) {
    const int row = blockIdx.x;
    const float x = xs[row];                 // broadcast load (L1 hit after lane 0)
    const float fif = floorf(x);
    const int fi = (int)fif;
    const float frac = x - fif;

    // Cubic values for the 4 overlapping basis polynomials (Horner).
    // B pointer is uniform + constant indices -> compiler emits s_load.
    float v0, v1, v2, v3;
    {
        float t;
        t = frac + 3.0f; v0 = ((B[0*4+3]*t + B[0*4+2])*t + B[0*4+1])*t + B[0*4+0];
        t = frac + 2.0f; v1 = ((B[1*4+3]*t + B[1*4+2])*t + B[1*4+1])*t + B[1*4+0];
        t = frac + 1.0f; v2 = ((B[2*4+3]*t + B[2*4+2])*t + B[2*4+1])*t + B[2*4+0];
        t = frac + 0.0f; v3 = ((B[3*4+3]*t + B[3*4+2])*t + B[3*4+1])*t + B[3*4+0];
    }

    float* outrow = out + (size_t)row * (size_t)n_knots;

    // Vectorized zero-stream with value insertion where the 4-wide span
    // [c, c+3] overlaps the nonzero window [fi, fi+3].
    const int nvec = n_knots & ~3;
    for (int c = threadIdx.x * 4; c < nvec; c += blockDim.x * 4) {
        float4 w = make_float4(0.0f, 0.0f, 0.0f, 0.0f);
        if (c + 3 >= fi && c <= fi + 3) {   // rare divergent path (1-2 threads/row)
            float* wp = (float*)&w;
            #pragma unroll
            for (int j = 0; j < 4; ++j) {
                const int k = (c + j) - fi;
                float val = 0.0f;
                if (k == 0) val = v0;
                else if (k == 1) val = v1;
                else if (k == 2) val = v2;
                else if (k == 3) val = v3;
                wp[j] = val;
            }
        }
        *(float4*)(outrow + c) = w;
    }
    // Scalar tail if n_knots % 4 != 0 (not hit for n=2048, kept for generality).
    for (int c = nvec + (int)threadIdx.x; c < n_knots; c += (int)blockDim.x) {
        const int k = c - fi;
        float val = 0.0f;
        if (k == 0) val = v0;
        else if (k == 1) val = v1;
        else if (k == 2) val = v2;
        else if (k == 3) val = v3;
        outrow[c] = val;
    }
}

extern "C" void kernel_launch(void* const* d_in, const int* in_sizes, int n_in,
                              void* d_out, int out_size, void* d_ws, size_t ws_size,
                              hipStream_t stream) {
    const float* xs = (const float*)d_in[0];
    const float* B  = (const float*)d_in[1];   // 16 floats (q=3)
    float* out = (float*)d_out;

    const int n_samples = in_sizes[0];                 // 131072
    const int n_knots   = out_size / n_samples;        // 2048

    bspline_row_kernel<<<n_samples, 256, 0, stream>>>(xs, B, out, n_knots);
}